// Round 11
// baseline (426.131 us; speedup 1.0000x reference)
//
#include <hip/hip_runtime.h>
#include <hip/hip_fp16.h>
#include <stdint.h>

#define CH 128
#define OC 64
#define NG 512
#define NBLK 256      // CSR-build blocks (== grid, co-resident)
#define NBMAX 4096    // max coarse buckets (nodes/256)
#define POOLB 400     // pool blocks
#define PADB 3840     // per-bucket pad reserve (15*256)

typedef unsigned int uint;
typedef unsigned short ushort;
typedef __attribute__((ext_vector_type(8))) _Float16 half8;
typedef __attribute__((ext_vector_type(4))) float floatx4;

__device__ __forceinline__ __half2 h2(uint u) { return *(__half2*)&u; }

// ---- software grid barrier: agent-scope release/acquire (cross-XCD safe) ----
__device__ __forceinline__ void gbar(int* bar, int phase) {
    __syncthreads();
    if (threadIdx.x == 0) {
        __hip_atomic_fetch_add(bar, 1, __ATOMIC_ACQ_REL, __HIP_MEMORY_SCOPE_AGENT);
        int target = phase * NBLK;
        while (__hip_atomic_load(bar, __ATOMIC_ACQUIRE, __HIP_MEMORY_SCOPE_AGENT) < target)
            __builtin_amdgcn_s_sleep(8);
    }
    __syncthreads();
}

// ==== fused CSR build: hist -> scan -> partition -> per-bucket finalize ====
// Grid MUST be NBLK blocks (all co-resident: 256 blocks on 256 CUs).
__global__ __launch_bounds__(256) void k_csrbuild(const int* __restrict__ esrc,
                                                  const int* __restrict__ edst,
                                                  int* __restrict__ bar,
                                                  int* __restrict__ bhT,
                                                  int* __restrict__ off,
                                                  int* __restrict__ segsum,
                                                  int* __restrict__ ebuf,
                                                  int* __restrict__ meta,
                                                  float* __restrict__ dinv,
                                                  int* __restrict__ ssrc,
                                                  int n, int NB, int E, int chunk) {
    __shared__ int ls[NBMAX];     // hist / part cursors / csr scratch
    __shared__ int ls2[256];      // scans
    int b = blockIdx.x, tid = threadIdx.x;

    // ---- phase A: per-block histogram over coarse buckets (bucket-major out)
    for (int j = tid; j < NB; j += 256) ls[j] = 0;
    __syncthreads();
    int lo = b * chunk, hi = min(E, lo + chunk);
    for (int i = lo + tid; i < hi; i += 256) atomicAdd(&ls[edst[i] >> 8], 1);
    __syncthreads();
    for (int j = tid; j < NB; j += 256) bhT[j * NBLK + b] = ls[j];
    gbar(bar, 1);

    // ---- phase B1: segment sums (block b scans bhT[b*NB .. b*NB+NB))
    int s0 = b * NB;
    int l0 = 2 * tid, l1 = 2 * tid + 1;
    int v0 = (l0 < NB) ? bhT[s0 + l0] : 0;
    int v1 = (l1 < NB) ? bhT[s0 + l1] : 0;
    int tsum = v0 + v1;
    int val = tsum;
    ls2[tid] = val; __syncthreads();
    for (int o = 1; o < 256; o <<= 1) {
        int t2 = (tid >= o) ? ls2[tid - o] : 0;
        __syncthreads();
        val += t2; ls2[tid] = val;
        __syncthreads();
    }
    int myexcl = val - tsum;
    if (tid == 255) segsum[b] = val;
    gbar(bar, 2);

    // ---- phase B2: global base + write exclusive scan
    ls2[tid] = segsum[tid]; __syncthreads();
    int sv = ls2[tid];
    int sval = sv;
    for (int o = 1; o < 256; o <<= 1) {
        int t2 = (tid >= o) ? ls2[tid - o] : 0;
        __syncthreads();
        sval += t2; ls2[tid] = sval;
        __syncthreads();
    }
    int base = (b > 0) ? ls2[b - 1] : 0;
    if (l0 < NB) off[s0 + l0] = base + myexcl;
    if (l1 < NB) off[s0 + l1] = base + myexcl + v0;
    gbar(bar, 3);

    // ---- phase C: partition edges into per-(bucket,block) segments
    for (int j = tid; j < NB; j += 256) ls[j] = off[j * NBLK + b];
    __syncthreads();
    for (int i = lo + tid; i < hi; i += 256) {
        int s = esrc[i], d = edst[i];
        int pos = atomicAdd(&ls[d >> 8], 1);
        ebuf[pos] = (s << 8) | (d & 255);
    }
    gbar(bar, 4);

    // ---- phase D: per-bucket CSR finalize (padded x16, sentinel = n)
    for (int bk = b; bk < NB; bk += NBLK) {
        int node0 = bk << 8;
        int bstart = off[bk * NBLK];
        int bend = (bk + 1 < NB) ? off[(bk + 1) * NBLK] : E;
        int base2 = bstart + bk * PADB;
        int rend = bend + (bk + 1) * PADB;
        for (int i = base2 + tid; i < rend; i += 256) ssrc[i] = n;
        ls[tid] = 0;
        __syncthreads();
        for (int i = bstart + tid; i < bend; i += 256)
            atomicAdd(&ls[ebuf[i] & 255], 1);
        __syncthreads();
        int dv = ls[tid];
        int degp = (dv + 15) & ~15;
        int dval = degp;
        ls2[tid] = dval; __syncthreads();
        for (int o = 1; o < 256; o <<= 1) {
            int t2 = (tid >= o) ? ls2[tid - o] : 0;
            __syncthreads();
            dval += t2; ls2[tid] = dval;
            __syncthreads();
        }
        int excl = dval - degp;
        int node = node0 + tid;
        if (node < n) {
            meta[node] = ((base2 + excl) << 7) | (degp >> 4);
            dinv[node] = rsqrtf((float)dv + 1.0f);
        }
        ls[1024 + tid] = base2 + excl;
        __syncthreads();
        for (int i = bstart + tid; i < bend; i += 256) {
            int e = ebuf[i];
            int pos = atomicAdd(&ls[1024 + (e & 255)], 1);
            ssrc[pos] = e >> 8;
        }
        __syncthreads();
    }
}

// -- fused: x->f16 pre-scaled (+sentinels) | Wt transp | Wc,bc | zero q/cnt --
__global__ __launch_bounds__(256) void k_cvtprep(const float* __restrict__ x,
                                                 const float* __restrict__ dinv,
                                                 const float* __restrict__ W1,
                                                 const float* __restrict__ W2,
                                                 const float* __restrict__ b2,
                                                 const float* __restrict__ Wfc,
                                                 const float* __restrict__ bfc,
                                                 ushort* __restrict__ xb,
                                                 ushort* __restrict__ yb,
                                                 ushort* __restrict__ Wt,
                                                 float* __restrict__ Wc,
                                                 float* __restrict__ bc,
                                                 float* __restrict__ q,
                                                 float* __restrict__ cnt,
                                                 int n, int cvtBlocks) {
    int bid = blockIdx.x, tid = threadIdx.x;
    if (bid < cvtBlocks) {
        int i = (bid * 256 + tid) * 4;
        if (i < n * CH) {
            float d = dinv[i >> 7];
            float4 v = *(const float4*)(x + i);
            __half2 h0 = __floats2half2_rn(v.x * d, v.y * d);
            __half2 h1v = __floats2half2_rn(v.z * d, v.w * d);
            uint2 o;
            o.x = *(uint*)&h0; o.y = *(uint*)&h1v;
            *(uint2*)(xb + i) = o;
        }
        if (bid == 0 && tid < CH) {
            xb[(size_t)n * CH + tid] = 0;    // sentinel rows
            yb[(size_t)n * CH + tid] = 0;
        }
        return;
    }
    int t = (bid - cvtBlocks) * 256 + tid;
    int pt = (gridDim.x - cvtBlocks) * 256;
    for (int z = t; z < NG * CH; z += pt) q[z] = 0.f;
    for (int z = t; z < NG; z += pt) cnt[z] = 0.f;
    if (t < CH * CH) {
        int nc = t >> 7, k = t & 127;
        Wt[nc * CH + k] = __half_as_ushort(__float2half(W1[k * CH + nc]));
    } else if (t < CH * CH + CH * OC) {
        int u = t - CH * CH;
        int k = u >> 6, o = u & 63;
        float acc = 0.f;
        for (int j = 0; j < CH; j++) acc += W2[k * CH + j] * Wfc[j * OC + o];
        Wc[u] = acc;
    } else if (t < CH * CH + CH * OC + OC) {
        int o = t - CH * CH - CH * OC;
        float acc = bfc[o];
        for (int j = 0; j < CH; j++) acc += b2[j] * Wfc[j * OC + o];
        bc[o] = acc;
    }
}

// ---- aggregation (R8 proven): quarter-wave, pad-16 CSR, f16 pk_add --------
// out = dinv_dst * (sum_e Hs[src_e] + Hs[dst]); Hs pre-scaled by dinv.
__global__ __launch_bounds__(256) void k_agg(const ushort* __restrict__ Hs,
                                             const int* __restrict__ meta,
                                             const int* __restrict__ ssrc,
                                             const float* __restrict__ dinv,
                                             ushort* __restrict__ out, int n) {
    int wid = (blockIdx.x << 2) | (threadIdx.x >> 6);
    if (wid >= n) return;
    int uw = __builtin_amdgcn_readfirstlane(wid);
    int lane = threadIdx.x & 63;
    int sub = lane >> 4;          // edge slot 0..3
    int li = lane & 15;           // 16 lanes x 8ch = 128 ch
    int c = li * 8;
    __half2 A0, A1, A2, A3;
    A0 = A1 = A2 = A3 = __floats2half2_rn(0.f, 0.f);
    if (sub == 0) {               // self term
        uint4 sv = *(const uint4*)(Hs + ((size_t)uw << 7) + c);
        A0 = h2(sv.x); A1 = h2(sv.y); A2 = h2(sv.z); A3 = h2(sv.w);
    }
    int mv = meta[uw];
    int e0 = mv >> 7;
    int iters = mv & 127;
    for (int it = 0; it < iters; ++it) {
        int e = e0 + (it << 4) + sub;
        int s0 = ssrc[e];
        int s1 = ssrc[e + 4];
        int s2 = ssrc[e + 8];
        int s3 = ssrc[e + 12];
        uint4 g0 = *(const uint4*)(Hs + (s0 << 7) + c);
        uint4 g1 = *(const uint4*)(Hs + (s1 << 7) + c);
        uint4 g2 = *(const uint4*)(Hs + (s2 << 7) + c);
        uint4 g3 = *(const uint4*)(Hs + (s3 << 7) + c);
        A0 = __hadd2(A0, __hadd2(__hadd2(h2(g0.x), h2(g1.x)), __hadd2(h2(g2.x), h2(g3.x))));
        A1 = __hadd2(A1, __hadd2(__hadd2(h2(g0.y), h2(g1.y)), __hadd2(h2(g2.y), h2(g3.y))));
        A2 = __hadd2(A2, __hadd2(__hadd2(h2(g0.z), h2(g1.z)), __hadd2(h2(g2.z), h2(g3.z))));
        A3 = __hadd2(A3, __hadd2(__hadd2(h2(g0.w), h2(g1.w)), __hadd2(h2(g2.w), h2(g3.w))));
    }
    float2 f0 = __half22float2(A0);
    float2 f1 = __half22float2(A1);
    float2 f2 = __half22float2(A2);
    float2 f3 = __half22float2(A3);
    float v0 = f0.x, v1 = f0.y, v2 = f1.x, v3 = f1.y;
    float v4 = f2.x, v5 = f2.y, v6 = f3.x, v7 = f3.y;
    v0 += __shfl_xor(v0, 16); v0 += __shfl_xor(v0, 32);
    v1 += __shfl_xor(v1, 16); v1 += __shfl_xor(v1, 32);
    v2 += __shfl_xor(v2, 16); v2 += __shfl_xor(v2, 32);
    v3 += __shfl_xor(v3, 16); v3 += __shfl_xor(v3, 32);
    v4 += __shfl_xor(v4, 16); v4 += __shfl_xor(v4, 32);
    v5 += __shfl_xor(v5, 16); v5 += __shfl_xor(v5, 32);
    v6 += __shfl_xor(v6, 16); v6 += __shfl_xor(v6, 32);
    v7 += __shfl_xor(v7, 16); v7 += __shfl_xor(v7, 32);
    if (sub == 0) {
        float d = dinv[uw];
        __half2 o0 = __floats2half2_rn(v0 * d, v1 * d);
        __half2 o1 = __floats2half2_rn(v2 * d, v3 * d);
        __half2 o2 = __floats2half2_rn(v4 * d, v5 * d);
        __half2 o3 = __floats2half2_rn(v6 * d, v7 * d);
        uint4 o;
        o.x = *(uint*)&o0; o.y = *(uint*)&o1;
        o.z = *(uint*)&o2; o.w = *(uint*)&o3;
        *(uint4*)(out + ((size_t)uw << 7) + c) = o;
    }
}

// ------ H = dinv*relu(Y*W + b) via MFMA f16 (R8 proven) ------
__global__ __launch_bounds__(256) void k_gemm_mfma(const ushort* __restrict__ Y,
                                                   const ushort* __restrict__ Wt,
                                                   const float* __restrict__ bias,
                                                   const float* __restrict__ dinv,
                                                   ushort* __restrict__ H, int n) {
    __shared__ __align__(16) ushort As[128][136];
    int tid = threadIdx.x;
    int r0 = blockIdx.x * 128;
#pragma unroll
    for (int i = 0; i < 8; i++) {
        int idx = tid + i * 256;
        int row = idx >> 4;
        int c8 = (idx & 15) * 8;
        int r = r0 + row;
        uint4 v = make_uint4(0u, 0u, 0u, 0u);
        if (r < n) v = *(const uint4*)(Y + (size_t)r * CH + c8);
        *(uint4*)&As[row][c8] = v;
    }
    __syncthreads();
    int w = tid >> 6, lane = tid & 63;
    int qm = lane & 15, quad = lane >> 4;
    floatx4 acc[2][8];
#pragma unroll
    for (int mi = 0; mi < 2; mi++)
#pragma unroll
        for (int nt = 0; nt < 8; nt++) acc[mi][nt] = (floatx4){0.f, 0.f, 0.f, 0.f};
#pragma unroll
    for (int ks = 0; ks < 4; ks++) {
        int k0 = ks * 32 + quad * 8;
        half8 va0 = *(const half8*)&As[w * 32 + qm][k0];
        half8 va1 = *(const half8*)&As[w * 32 + 16 + qm][k0];
#pragma unroll
        for (int nt = 0; nt < 8; nt++) {
            half8 bf = *(const half8*)(Wt + (nt * 16 + qm) * CH + k0);
            acc[0][nt] = __builtin_amdgcn_mfma_f32_16x16x32_f16(va0, bf, acc[0][nt], 0, 0, 0);
            acc[1][nt] = __builtin_amdgcn_mfma_f32_16x16x32_f16(va1, bf, acc[1][nt], 0, 0, 0);
        }
    }
#pragma unroll
    for (int mi = 0; mi < 2; mi++) {
#pragma unroll
        for (int reg = 0; reg < 4; reg++) {
            int r = r0 + w * 32 + mi * 16 + quad * 4 + reg;
            if (r >= n) continue;
            float d = dinv[r];
#pragma unroll
            for (int nt = 0; nt < 8; nt++) {
                int cidx = nt * 16 + qm;
                float val = fmaxf(acc[mi][nt][reg] + bias[cidx], 0.f) * d;
                H[(size_t)r * CH + cidx] = __half_as_ushort(__float2half(val));
            }
        }
    }
}

// -------- pool: node-range sweep over f16 rows, fp32 atomics flush ---------
__global__ __launch_bounds__(256) void k_pool(const ushort* __restrict__ Z,
                                              const int* __restrict__ batch,
                                              float* __restrict__ Qs,
                                              float* __restrict__ cnt,
                                              int n, int npb) {
    int lo = blockIdx.x * npb;
    if (lo >= n) return;
    int hi = min(n, lo + npb);
    int w = threadIdx.x >> 6, lane = threadIdx.x & 63;
    int c = lane * 2;
    float a0 = 0.f, a1 = 0.f;
    int curg = -1, rc = 0;
    for (int i = lo + w; i < hi; i += 4) {
        int g = batch[i];
        if (g != curg) {
            if (rc > 0) {
                atomicAdd(&Qs[curg * CH + c], a0);
                atomicAdd(&Qs[curg * CH + c + 1], a1);
                if (lane == 0) atomicAdd(&cnt[curg], (float)rc);
            }
            curg = g; a0 = a1 = 0.f; rc = 0;
        }
        uint v = *(const uint*)(Z + (size_t)i * CH + c);
        float2 f = __half22float2(h2(v));
        a0 += f.x; a1 += f.y; rc++;
    }
    if (rc > 0) {
        atomicAdd(&Qs[curg * CH + c], a0);
        atomicAdd(&Qs[curg * CH + c + 1], a1);
        if (lane == 0) atomicAdd(&cnt[curg], (float)rc);
    }
}

// ---------------- out = (Qs/cnt)*Wc + bc ----------------
__global__ __launch_bounds__(256) void k_out(const float* __restrict__ Qs,
                                             const float* __restrict__ cnt,
                                             const float* __restrict__ Wc,
                                             const float* __restrict__ bc,
                                             float* __restrict__ out) {
    int t = blockIdx.x * 256 + threadIdx.x;
    int g = t >> 6, o = t & 63;
    float invc = 1.f / fmaxf(cnt[g], 1.f);
    float acc = 0.f;
    for (int k = 0; k < CH; k++) acc += Qs[g * CH + k] * Wc[k * OC + o];
    out[t] = acc * invc + bc[o];
}

extern "C" void kernel_launch(void* const* d_in, const int* in_sizes, int n_in,
                              void* d_out, int out_size, void* d_ws, size_t ws_size,
                              hipStream_t stream) {
    const float* x   = (const float*)d_in[0];
    const float* W1  = (const float*)d_in[1];
    const float* b1  = (const float*)d_in[2];
    const float* W2  = (const float*)d_in[3];
    const float* b2  = (const float*)d_in[4];
    const float* Wfc = (const float*)d_in[5];
    const float* bfc = (const float*)d_in[6];
    const int* edges = (const int*)d_in[7];
    const int* batch = (const int*)d_in[8];

    const int n = in_sizes[8];        // 100000
    const int E = in_sizes[7] / 2;    // 1600000
    const int* esrc = edges;
    const int* edst = edges + E;

    const int NB = (n + 255) >> 8;            // 391 coarse buckets
    const int T = NB * NBLK;
    const int chunk = (E + NBLK - 1) / NBLK;

    char* p = (char*)d_ws;
    auto carve = [&](size_t bytes) {
        void* r = (void*)p;
        p += (bytes + 255) & ~(size_t)255;
        return r;
    };
    int*    bar       = (int*)carve(256);
    int*    bhT       = (int*)carve((size_t)T * 4);
    int*    off       = (int*)carve((size_t)T * 4);
    int*    segsum    = (int*)carve(1024);
    int*    ebuf      = (int*)carve((size_t)E * 4);
    int*    meta      = (int*)carve((size_t)n * 4);
    float*  dinv      = (float*)carve((size_t)n * 4);
    int*    ssrc      = (int*)carve(((size_t)E + (size_t)NB * PADB) * 4);
    ushort* xb        = (ushort*)carve((size_t)(n + 1) * CH * 2);  // x, later h1
    ushort* yb        = (ushort*)carve((size_t)(n + 1) * CH * 2);  // y, later z
    ushort* Wt        = (ushort*)carve((size_t)CH * CH * 2);
    float*  q         = (float*)carve((size_t)NG * CH * 4);
    float*  cnt       = (float*)carve((size_t)NG * 4);
    float*  Wc        = (float*)carve((size_t)CH * OC * 4);
    float*  bc        = (float*)carve((size_t)OC * 4);

    int cvtBlocks = (n * CH / 4 + 255) / 256;
    int prepBlocks = (CH * CH + CH * OC + OC + 255) / 256;
    int npb = (n + POOLB - 1) / POOLB;

    // barrier counter must start at 0 (ws is poisoned 0xAA)
    hipMemsetAsync(bar, 0, 256, stream);

    // fused CSR build: hist -> scan -> partition -> finalize (1 kernel)
    k_csrbuild<<<NBLK, 256, 0, stream>>>(esrc, edst, bar, bhT, off, segsum,
                                         ebuf, meta, dinv, ssrc, n, NB, E, chunk);
    // feature conversion + weight prep + q/cnt zero (1 kernel)
    k_cvtprep<<<cvtBlocks + prepBlocks, 256, 0, stream>>>(
        x, dinv, W1, W2, b2, Wfc, bfc, xb, yb, Wt, Wc, bc, q, cnt, n, cvtBlocks);
    // y = dinv*(sum Xs + self)   (xb -> yb)
    k_agg<<<(n + 3) / 4, 256, 0, stream>>>(xb, meta, ssrc, dinv, yb, n);
    // h1s = dinv*relu(y*W1 + b1)   (yb -> xb; sentinel row stays 0)
    k_gemm_mfma<<<(n + 127) / 128, 256, 0, stream>>>(yb, Wt, b1, dinv, xb, n);
    // z = dinv*(sum H1s + self)   (xb -> yb)
    k_agg<<<(n + 3) / 4, 256, 0, stream>>>(xb, meta, ssrc, dinv, yb, n);
    // q = sum-pool(z), cnt via atomics
    k_pool<<<POOLB, 256, 0, stream>>>(yb, batch, q, cnt, n, npb);
    // out = (q/cnt)*Wc + bc
    k_out<<<(NG * OC + 255) / 256, 256, 0, stream>>>(q, cnt, Wc, bc, (float*)d_out);
}